// Round 1
// baseline (1377.638 us; speedup 1.0000x reference)
//
#include <hip/hip_runtime.h>
#include <cmath>

#define TPB 256

static const int NTOK  = 1025;        // tokens incl CLS
static const int DIM   = 768;
static const int HEADS = 12;
static const int DH    = 64;
static const int QK3   = 2304;        // 3*768
static const int ROWS  = 4 * NTOK;    // 4100
static const int MROWS = 4 * (NTOK - 1); // 4096
static const size_t OUT0 = (size_t)ROWS * DIM; // 3148800 floats (first output)

// workspace offsets, in floats (o12 aliases qkv: qkv dead after k_prep)
static const size_t OFF_QKV  = 0;          // 9,446,400
static const size_t OFF_QKVM = 9446400;    // 9,437,184
static const size_t OFF_QE   = 18883584;   // 3,148,800
static const size_t OFF_KE   = 22032384;   // 3,148,800
static const size_t OFF_V2   = 25181184;   // 6,297,600
static const size_t OFF_CMAX = 31478784;   // 9,216
static const size_t OFF_UPD  = 31488000;   // 4,100
static const size_t OFF_O12  = 0;          // alias qkv

// ---------------------------------------------------------------------------
// K1: qkv = x @ w^T  (z=0, M=4100)   |   qkv_m = mask @ |w|^T (z=1, M=4096)
// 128x128x8 SGEMM, 8x8 microtile, B stored [N,K] (row-major weights)
// ---------------------------------------------------------------------------
__global__ __launch_bounds__(TPB)
void k_gemm_qkv(const float* __restrict__ x, const float* __restrict__ mask,
                const float* __restrict__ w, float* __restrict__ qkv,
                float* __restrict__ qkvm)
{
    const int z = blockIdx.z;
    const float* __restrict__ A = z ? mask : x;
    float* __restrict__ C = z ? qkvm : qkv;
    const int M = z ? MROWS : ROWS;

    __shared__ float As[8][128];
    __shared__ float Bs[8][128];

    const int t  = threadIdx.x;
    const int tx = t & 15, ty = t >> 4;
    const int rowT = blockIdx.y * 128, colT = blockIdx.x * 128;
    const int lr = t >> 1, lk = (t & 1) * 4;
    const int arow = rowT + lr;
    const int brow = colT + lr;
    const bool aval = arow < M;
    const float* Ap = A + (size_t)arow * DIM + lk;
    const float* Bp = w + (size_t)brow * DIM + lk;

    float acc[8][8];
#pragma unroll
    for (int i = 0; i < 8; ++i)
#pragma unroll
        for (int j = 0; j < 8; ++j) acc[i][j] = 0.f;

    for (int k0 = 0; k0 < DIM; k0 += 8) {
        float4 av = make_float4(0.f, 0.f, 0.f, 0.f);
        if (aval) av = *(const float4*)(Ap + k0);
        float4 bv = *(const float4*)(Bp + k0);
        if (z) { bv.x = fabsf(bv.x); bv.y = fabsf(bv.y); bv.z = fabsf(bv.z); bv.w = fabsf(bv.w); }
        __syncthreads();
        As[lk + 0][lr] = av.x; As[lk + 1][lr] = av.y; As[lk + 2][lr] = av.z; As[lk + 3][lr] = av.w;
        Bs[lk + 0][lr] = bv.x; Bs[lk + 1][lr] = bv.y; Bs[lk + 2][lr] = bv.z; Bs[lk + 3][lr] = bv.w;
        __syncthreads();
#pragma unroll
        for (int k = 0; k < 8; ++k) {
            float ar[8], br[8];
            *(float4*)&ar[0] = *(const float4*)&As[k][ty * 4];
            *(float4*)&ar[4] = *(const float4*)&As[k][64 + ty * 4];
            *(float4*)&br[0] = *(const float4*)&Bs[k][tx * 4];
            *(float4*)&br[4] = *(const float4*)&Bs[k][64 + tx * 4];
#pragma unroll
            for (int i = 0; i < 8; ++i)
#pragma unroll
                for (int j = 0; j < 8; ++j)
                    acc[i][j] = fmaf(ar[i], br[j], acc[i][j]);
        }
    }
#pragma unroll
    for (int i = 0; i < 8; ++i) {
        const int r = rowT + ((i < 4) ? (ty * 4 + i) : (64 + ty * 4 + i - 4));
        if (r < M) {
#pragma unroll
            for (int g = 0; g < 2; ++g) {
                float4 v = make_float4(acc[i][g * 4 + 0], acc[i][g * 4 + 1],
                                       acc[i][g * 4 + 2], acc[i][g * 4 + 3]);
                *(float4*)(C + (size_t)r * QK3 + colT + g * 64 + tx * 4) = v;
            }
        }
    }
}

// ---------------------------------------------------------------------------
// K2a: column max of qkv_m over the 1024 tokens, per (b, col)
// ---------------------------------------------------------------------------
__global__ __launch_bounds__(TPB)
void k_colmax(const float* __restrict__ qkvm, float* __restrict__ cmax)
{
    __shared__ float red[4][64];
    const int t = threadIdx.x;
    const int cl = t & 63, rg = t >> 6;
    const int col = blockIdx.x * 64 + cl;   // grid.x = 36 -> col < 2304
    const int b = blockIdx.y;
    const float* p = qkvm + (size_t)b * 1024 * QK3 + col;
    float mx = 0.f;  // qkv_m >= 0 always (mask>=0, |w|>=0)
    const int n0 = rg * 256;
    for (int n = 0; n < 256; ++n) mx = fmaxf(mx, p[(size_t)(n0 + n) * QK3]);
    red[rg][cl] = mx;
    __syncthreads();
    if (rg == 0) {
        mx = fmaxf(fmaxf(red[0][cl], red[1][cl]), fmaxf(red[2][cl], red[3][cl]));
        cmax[b * QK3 + col] = mx;
    }
}

// ---------------------------------------------------------------------------
// K2b: updated[b,n] = (n==0) ? 1 : any(mask[b,n-1,:] > 0)
// ---------------------------------------------------------------------------
__global__ __launch_bounds__(TPB)
void k_upd(const float* __restrict__ mask, float* __restrict__ upd)
{
    const int w = threadIdx.x >> 6, lane = threadIdx.x & 63;
    const int r = blockIdx.x * 4 + w;       // grid = 1025 -> r < 4100
    if (r >= ROWS) return;
    const int b = r / NTOK, n = r % NTOK;
    float res = 1.f;
    if (n > 0) {
        const float* p = mask + (size_t)(b * (NTOK - 1) + (n - 1)) * DIM;
        float s = 0.f;
        for (int i = lane; i < DIM; i += 64) s += p[i];
#pragma unroll
        for (int off = 32; off > 0; off >>= 1) s += __shfl_xor(s, off, 64);
        res = (s > 0.f) ? 1.f : 0.f;
    }
    if (lane == 0) upd[r] = res;
}

// ---------------------------------------------------------------------------
// K3: build q_eff = q*q_m*scale, k_eff = k*k_m, V2 = [v*v_m | v_m]  ([bh,n,128])
// ---------------------------------------------------------------------------
__global__ __launch_bounds__(TPB)
void k_prep(const float* __restrict__ qkv, const float* __restrict__ qkvm,
            const float* __restrict__ cmax, float* __restrict__ qe,
            float* __restrict__ ke, float* __restrict__ v2)
{
    const int idx = blockIdx.x * TPB + threadIdx.x;  // 12300*256 = 3,148,800 exact
    const int d = idx & 63;
    const int rest = idx >> 6;
    const int n = rest % NTOK;
    const int bh = rest / NTOK;
    const int h = bh % HEADS, b = bh / HEADS;
    const int col = h * DH + d;
    const size_t qrow = (size_t)(b * NTOK + n) * QK3;
    const float q = qkv[qrow + col];
    const float k = qkv[qrow + DIM + col];
    const float v = qkv[qrow + 2 * DIM + col];
    float qm = 1.f, km = 1.f, vm = 1.f;
    if (n > 0) {
        const size_t mrow = (size_t)(b * (NTOK - 1) + (n - 1)) * QK3;
        qm = qkvm[mrow + col]           / (1e-6f + cmax[b * QK3 + col]);
        km = qkvm[mrow + DIM + col]     / (1e-6f + cmax[b * QK3 + DIM + col]);
        vm = qkvm[mrow + 2 * DIM + col] / (1e-6f + cmax[b * QK3 + 2 * DIM + col]);
    }
    qe[idx] = q * qm * 0.125f;   // fold scale = 64^-0.5
    ke[idx] = k * km;
    const size_t v2off = (size_t)(bh * NTOK + n) * 128 + d;
    v2[v2off]      = v * vm;     // -> out path
    v2[v2off + 64] = vm;         // -> m path
}

// ---------------------------------------------------------------------------
// K4: flash attention, BM=BN=64, 128-wide V2, online softmax.
// o12[bh,n,0:64] = softmax(QK^T) @ (v_m*v);  o12[bh,n,64:128] = same @ v_m
// ---------------------------------------------------------------------------
__global__ __launch_bounds__(TPB)
void k_attn(const float* __restrict__ qe, const float* __restrict__ ke,
            const float* __restrict__ v2, float* __restrict__ o12)
{
    __shared__ float Qs[64][68];
    __shared__ float Ks[64][68];   // reused as P after S is computed
    __shared__ float Vs[64][132];

    const int t = threadIdx.x;
    const int tx = t & 15, ty = t >> 4;
    const int bh = blockIdx.y;
    const int q0 = blockIdx.x * 64;
    const float* qb = qe + (size_t)bh * NTOK * DH;
    const float* kb = ke + (size_t)bh * NTOK * DH;
    const float* vb = v2 + (size_t)bh * NTOK * 128;

#pragma unroll
    for (int li = 0; li < 4; ++li) {
        const int row = li * 16 + ty;
        const int qn = q0 + row;
        float4 val = make_float4(0.f, 0.f, 0.f, 0.f);
        if (qn < NTOK) val = *(const float4*)(qb + (size_t)qn * DH + tx * 4);
        *(float4*)&Qs[row][tx * 4] = val;
    }

    float m_i[4], l_i[4], acc[4][8];
#pragma unroll
    for (int i = 0; i < 4; ++i) {
        m_i[i] = -INFINITY; l_i[i] = 0.f;
#pragma unroll
        for (int c = 0; c < 8; ++c) acc[i][c] = 0.f;
    }

    for (int kt = 0; kt < 17; ++kt) {
        const int kn0 = kt * 64;
        __syncthreads();   // previous tile's P/V reads done before overwrite
#pragma unroll
        for (int li = 0; li < 4; ++li) {
            const int row = li * 16 + ty;
            const int kn = kn0 + row;
            float4 val = make_float4(0.f, 0.f, 0.f, 0.f);
            if (kn < NTOK) val = *(const float4*)(kb + (size_t)kn * DH + tx * 4);
            *(float4*)&Ks[row][tx * 4] = val;
        }
#pragma unroll
        for (int li = 0; li < 8; ++li) {
            const int row = (li & 3) * 16 + ty;
            const int kn = kn0 + row;
            const int c = tx * 4 + (li >> 2) * 64;
            float4 val = make_float4(0.f, 0.f, 0.f, 0.f);
            if (kn < NTOK) val = *(const float4*)(vb + (size_t)kn * 128 + c);
            *(float4*)&Vs[row][c] = val;
        }
        __syncthreads();

        // S = Q K^T : 4x4 microtile, rows ty+16i, cols tx+16j (conflict-free strides)
        float s[4][4];
#pragma unroll
        for (int i = 0; i < 4; ++i)
#pragma unroll
            for (int j = 0; j < 4; ++j) s[i][j] = 0.f;
#pragma unroll
        for (int k4 = 0; k4 < 64; k4 += 4) {
            float4 qv[4], kv[4];
#pragma unroll
            for (int i = 0; i < 4; ++i) qv[i] = *(const float4*)&Qs[ty + 16 * i][k4];
#pragma unroll
            for (int j = 0; j < 4; ++j) kv[j] = *(const float4*)&Ks[tx + 16 * j][k4];
#pragma unroll
            for (int i = 0; i < 4; ++i)
#pragma unroll
                for (int j = 0; j < 4; ++j)
                    s[i][j] += qv[i].x * kv[j].x + qv[i].y * kv[j].y +
                               qv[i].z * kv[j].z + qv[i].w * kv[j].w;
        }
#pragma unroll
        for (int j = 0; j < 4; ++j) {
            if (kn0 + tx + 16 * j >= NTOK) {
#pragma unroll
                for (int i = 0; i < 4; ++i) s[i][j] = -INFINITY;
            }
        }

        float alpha[4];
#pragma unroll
        for (int i = 0; i < 4; ++i) {
            float mx = fmaxf(fmaxf(s[i][0], s[i][1]), fmaxf(s[i][2], s[i][3]));
#pragma unroll
            for (int off = 8; off > 0; off >>= 1) mx = fmaxf(mx, __shfl_xor(mx, off, 16));
            const float mnew = fmaxf(m_i[i], mx);
            float sum = 0.f;
#pragma unroll
            for (int j = 0; j < 4; ++j) {
                const float p = __expf(s[i][j] - mnew);
                s[i][j] = p; sum += p;
            }
#pragma unroll
            for (int off = 8; off > 0; off >>= 1) sum += __shfl_xor(sum, off, 16);
            alpha[i] = __expf(m_i[i] - mnew);
            l_i[i] = l_i[i] * alpha[i] + sum;
            m_i[i] = mnew;
        }
        __syncthreads();   // all S-phase Ks reads complete
#pragma unroll
        for (int i = 0; i < 4; ++i)
#pragma unroll
            for (int j = 0; j < 4; ++j) Ks[ty + 16 * i][tx + 16 * j] = s[i][j];
#pragma unroll
        for (int i = 0; i < 4; ++i)
#pragma unroll
            for (int c = 0; c < 8; ++c) acc[i][c] *= alpha[i];
        __syncthreads();   // P visible

        for (int jj = 0; jj < 64; ++jj) {
            float pj[4];
#pragma unroll
            for (int i = 0; i < 4; ++i) pj[i] = Ks[ty + 16 * i][jj];
            const float4 v0 = *(const float4*)&Vs[jj][tx * 4];
            const float4 v1 = *(const float4*)&Vs[jj][tx * 4 + 64];
#pragma unroll
            for (int i = 0; i < 4; ++i) {
                acc[i][0] = fmaf(pj[i], v0.x, acc[i][0]);
                acc[i][1] = fmaf(pj[i], v0.y, acc[i][1]);
                acc[i][2] = fmaf(pj[i], v0.z, acc[i][2]);
                acc[i][3] = fmaf(pj[i], v0.w, acc[i][3]);
                acc[i][4] = fmaf(pj[i], v1.x, acc[i][4]);
                acc[i][5] = fmaf(pj[i], v1.y, acc[i][5]);
                acc[i][6] = fmaf(pj[i], v1.z, acc[i][6]);
                acc[i][7] = fmaf(pj[i], v1.w, acc[i][7]);
            }
        }
    }

#pragma unroll
    for (int i = 0; i < 4; ++i) {
        const int qn = q0 + ty + 16 * i;
        if (qn < NTOK) {
            const float inv = 1.f / l_i[i];
            float* op = o12 + (size_t)(bh * NTOK + qn) * 128;
            float4 r0 = make_float4(acc[i][0] * inv, acc[i][1] * inv, acc[i][2] * inv, acc[i][3] * inv);
            float4 r1 = make_float4(acc[i][4] * inv, acc[i][5] * inv, acc[i][6] * inv, acc[i][7] * inv);
            *(float4*)(op + tx * 4) = r0;
            *(float4*)(op + 64 + tx * 4) = r1;
        }
    }
}

// ---------------------------------------------------------------------------
// K5: z=0: out = (o1 * updated) @ w_out^T + b_out  -> d_out[0 : 4100*768]
//     z=1: m   = (o2 * updated) @ |w_out|^T, rows n>=1 -> d_out[OUT0 : +4096*768]
// ---------------------------------------------------------------------------
__global__ __launch_bounds__(TPB)
void k_gemm_out(const float* __restrict__ o12, const float* __restrict__ upd,
                const float* __restrict__ wout, const float* __restrict__ bout,
                float* __restrict__ dout)
{
    const int z = blockIdx.z;
    __shared__ float As[8][128];
    __shared__ float Bs[8][128];

    const int t = threadIdx.x;
    const int tx = t & 15, ty = t >> 4;
    const int rowT = blockIdx.y * 128, colT = blockIdx.x * 128;
    const int lr = t >> 1, lk = (t & 1) * 4;
    const int arow = rowT + lr;
    const bool aval = arow < ROWS;
    const int ab = aval ? (arow / NTOK) : 0;
    const int an = aval ? (arow % NTOK) : 0;
    const float u = aval ? upd[arow] : 0.f;
    const int brow = colT + lr;   // grid.x=6 -> brow < 768 always
    const float* Bp = wout + (size_t)brow * DIM + lk;
    const size_t abase = ((size_t)ab * HEADS * NTOK + an) * 128 + (z ? 64 : 0);

    float acc[8][8];
#pragma unroll
    for (int i = 0; i < 8; ++i)
#pragma unroll
        for (int j = 0; j < 8; ++j) acc[i][j] = 0.f;

    for (int k0 = 0; k0 < DIM; k0 += 8) {
        const int c = k0 + lk;
        const int h = c >> 6, d = c & 63;
        float4 av = make_float4(0.f, 0.f, 0.f, 0.f);
        if (aval) {
            av = *(const float4*)(o12 + abase + (size_t)h * NTOK * 128 + d);
            av.x *= u; av.y *= u; av.z *= u; av.w *= u;
        }
        float4 bv = *(const float4*)(Bp + k0);
        if (z) { bv.x = fabsf(bv.x); bv.y = fabsf(bv.y); bv.z = fabsf(bv.z); bv.w = fabsf(bv.w); }
        __syncthreads();
        As[lk + 0][lr] = av.x; As[lk + 1][lr] = av.y; As[lk + 2][lr] = av.z; As[lk + 3][lr] = av.w;
        Bs[lk + 0][lr] = bv.x; Bs[lk + 1][lr] = bv.y; Bs[lk + 2][lr] = bv.z; Bs[lk + 3][lr] = bv.w;
        __syncthreads();
#pragma unroll
        for (int k = 0; k < 8; ++k) {
            float ar[8], br[8];
            *(float4*)&ar[0] = *(const float4*)&As[k][ty * 4];
            *(float4*)&ar[4] = *(const float4*)&As[k][64 + ty * 4];
            *(float4*)&br[0] = *(const float4*)&Bs[k][tx * 4];
            *(float4*)&br[4] = *(const float4*)&Bs[k][64 + tx * 4];
#pragma unroll
            for (int i = 0; i < 8; ++i)
#pragma unroll
                for (int j = 0; j < 8; ++j)
                    acc[i][j] = fmaf(ar[i], br[j], acc[i][j]);
        }
    }
#pragma unroll
    for (int i = 0; i < 8; ++i) {
        const int r = rowT + ((i < 4) ? (ty * 4 + i) : (64 + ty * 4 + i - 4));
        if (r >= ROWS) continue;
        const int b = r / NTOK, n = r % NTOK;
#pragma unroll
        for (int g = 0; g < 2; ++g) {
            const int col = colT + g * 64 + tx * 4;
            float4 v = make_float4(acc[i][g * 4 + 0], acc[i][g * 4 + 1],
                                   acc[i][g * 4 + 2], acc[i][g * 4 + 3]);
            if (z == 0) {
                const float4 bb = *(const float4*)(bout + col);
                v.x += bb.x; v.y += bb.y; v.z += bb.z; v.w += bb.w;
                *(float4*)(dout + (size_t)r * DIM + col) = v;
            } else if (n >= 1) {
                *(float4*)(dout + OUT0 + ((size_t)(b * (NTOK - 1) + (n - 1))) * DIM + col) = v;
            }
        }
    }
}

extern "C" void kernel_launch(void* const* d_in, const int* in_sizes, int n_in,
                              void* d_out, int out_size, void* d_ws, size_t ws_size,
                              hipStream_t stream)
{
    const float* x    = (const float*)d_in[0];
    const float* mask = (const float*)d_in[1];
    const float* wqkv = (const float*)d_in[2];
    const float* wout = (const float*)d_in[3];
    const float* bout = (const float*)d_in[4];
    float* ws   = (float*)d_ws;
    float* qkv  = ws + OFF_QKV;
    float* qkvm = ws + OFF_QKVM;
    float* qe   = ws + OFF_QE;
    float* ke   = ws + OFF_KE;
    float* v2   = ws + OFF_V2;
    float* cmax = ws + OFF_CMAX;
    float* upd  = ws + OFF_UPD;
    float* o12  = ws + OFF_O12;   // aliases qkv (dead after k_prep)
    float* out  = (float*)d_out;

    hipLaunchKernelGGL(k_gemm_qkv, dim3(18, 33, 2), dim3(TPB), 0, stream, x, mask, wqkv, qkv, qkvm);
    hipLaunchKernelGGL(k_colmax,   dim3(36, 4),     dim3(TPB), 0, stream, qkvm, cmax);
    hipLaunchKernelGGL(k_upd,      dim3(1025),      dim3(TPB), 0, stream, mask, upd);
    hipLaunchKernelGGL(k_prep,     dim3(12300),     dim3(TPB), 0, stream, qkv, qkvm, cmax, qe, ke, v2);
    hipLaunchKernelGGL(k_attn,     dim3(17, 48),    dim3(TPB), 0, stream, qe, ke, v2, o12);
    hipLaunchKernelGGL(k_gemm_out, dim3(6, 33, 2),  dim3(TPB), 0, stream, o12, upd, wout, bout, out);
}

// Round 2
// 813.111 us; speedup vs baseline: 1.6943x; 1.6943x over previous
//
#include <hip/hip_runtime.h>
#include <cmath>

#define TPB 256

static const int NTOK  = 1025;
static const int DIM   = 768;
static const int HEADS = 12;
static const int DH    = 64;
static const int QK3   = 2304;
static const int ROWS  = 4 * NTOK;        // 4100
static const int MROWS = 4 * (NTOK - 1);  // 4096
static const int NPAD  = 1088;            // 17*64, row padding for q/k/vt
static const size_t OUT0 = (size_t)ROWS * DIM;

// workspace offsets in floats
static const size_t OFF_QKV  = 0;          // 9,446,400 f
static const size_t OFF_QKVM = 9446400;    // 9,437,184 f
static const size_t OFF_QE   = 18883584;   // 48*1088*64 bf16 = 1,671,168 f
static const size_t OFF_KE   = 20554752;   // 1,671,168 f
static const size_t OFF_VT   = 22225920;   // 48*128*1088 bf16 = 3,342,336 f
static const size_t OFF_CMAX = 25568256;   // 9,216 f
static const size_t OFF_UPD  = 25577472;   // 4,100 f
static const size_t OFF_O12  = 0;          // alias qkv (dead after k_prep)

typedef __attribute__((ext_vector_type(8))) short short8;
typedef __attribute__((ext_vector_type(4))) float f32x4;

__device__ __forceinline__ unsigned short f2bf(float f) {
    union { float f; unsigned int u; } c; c.f = f;
    unsigned int u = c.u + 0x7fffu + ((c.u >> 16) & 1u);  // RNE (no NaN inputs here)
    return (unsigned short)(u >> 16);
}

// ---------------------------------------------------------------------------
// K1: qkv = x @ w^T (z=0) | qkv_m = mask @ |w|^T (z=1). fp32 SGEMM (unchanged)
// ---------------------------------------------------------------------------
__global__ __launch_bounds__(TPB)
void k_gemm_qkv(const float* __restrict__ x, const float* __restrict__ mask,
                const float* __restrict__ w, float* __restrict__ qkv,
                float* __restrict__ qkvm)
{
    const int z = blockIdx.z;
    const float* __restrict__ A = z ? mask : x;
    float* __restrict__ C = z ? qkvm : qkv;
    const int M = z ? MROWS : ROWS;

    __shared__ float As[8][128];
    __shared__ float Bs[8][128];

    const int t  = threadIdx.x;
    const int tx = t & 15, ty = t >> 4;
    const int rowT = blockIdx.y * 128, colT = blockIdx.x * 128;
    const int lr = t >> 1, lk = (t & 1) * 4;
    const int arow = rowT + lr;
    const int brow = colT + lr;
    const bool aval = arow < M;
    const float* Ap = A + (size_t)arow * DIM + lk;
    const float* Bp = w + (size_t)brow * DIM + lk;

    float acc[8][8];
#pragma unroll
    for (int i = 0; i < 8; ++i)
#pragma unroll
        for (int j = 0; j < 8; ++j) acc[i][j] = 0.f;

    for (int k0 = 0; k0 < DIM; k0 += 8) {
        float4 av = make_float4(0.f, 0.f, 0.f, 0.f);
        if (aval) av = *(const float4*)(Ap + k0);
        float4 bv = *(const float4*)(Bp + k0);
        if (z) { bv.x = fabsf(bv.x); bv.y = fabsf(bv.y); bv.z = fabsf(bv.z); bv.w = fabsf(bv.w); }
        __syncthreads();
        As[lk + 0][lr] = av.x; As[lk + 1][lr] = av.y; As[lk + 2][lr] = av.z; As[lk + 3][lr] = av.w;
        Bs[lk + 0][lr] = bv.x; Bs[lk + 1][lr] = bv.y; Bs[lk + 2][lr] = bv.z; Bs[lk + 3][lr] = bv.w;
        __syncthreads();
#pragma unroll
        for (int k = 0; k < 8; ++k) {
            float ar[8], br[8];
            *(float4*)&ar[0] = *(const float4*)&As[k][ty * 4];
            *(float4*)&ar[4] = *(const float4*)&As[k][64 + ty * 4];
            *(float4*)&br[0] = *(const float4*)&Bs[k][tx * 4];
            *(float4*)&br[4] = *(const float4*)&Bs[k][64 + tx * 4];
#pragma unroll
            for (int i = 0; i < 8; ++i)
#pragma unroll
                for (int j = 0; j < 8; ++j)
                    acc[i][j] = fmaf(ar[i], br[j], acc[i][j]);
        }
    }
#pragma unroll
    for (int i = 0; i < 8; ++i) {
        const int r = rowT + ((i < 4) ? (ty * 4 + i) : (64 + ty * 4 + i - 4));
        if (r < M) {
#pragma unroll
            for (int g = 0; g < 2; ++g) {
                float4 v = make_float4(acc[i][g * 4 + 0], acc[i][g * 4 + 1],
                                       acc[i][g * 4 + 2], acc[i][g * 4 + 3]);
                *(float4*)(C + (size_t)r * QK3 + colT + g * 64 + tx * 4) = v;
            }
        }
    }
}

// ---------------------------------------------------------------------------
// K2a: column max of qkv_m over the 1024 tokens, per (b, col)
// ---------------------------------------------------------------------------
__global__ __launch_bounds__(TPB)
void k_colmax(const float* __restrict__ qkvm, float* __restrict__ cmax)
{
    __shared__ float red[4][64];
    const int t = threadIdx.x;
    const int cl = t & 63, rg = t >> 6;
    const int col = blockIdx.x * 64 + cl;
    const int b = blockIdx.y;
    const float* p = qkvm + (size_t)b * 1024 * QK3 + col;
    float mx = 0.f;
    const int n0 = rg * 256;
    for (int n = 0; n < 256; ++n) mx = fmaxf(mx, p[(size_t)(n0 + n) * QK3]);
    red[rg][cl] = mx;
    __syncthreads();
    if (rg == 0) {
        mx = fmaxf(fmaxf(red[0][cl], red[1][cl]), fmaxf(red[2][cl], red[3][cl]));
        cmax[b * QK3 + col] = mx;
    }
}

// ---------------------------------------------------------------------------
// K2b: updated[b,n]
// ---------------------------------------------------------------------------
__global__ __launch_bounds__(TPB)
void k_upd(const float* __restrict__ mask, float* __restrict__ upd)
{
    const int w = threadIdx.x >> 6, lane = threadIdx.x & 63;
    const int r = blockIdx.x * 4 + w;
    if (r >= ROWS) return;
    const int b = r / NTOK, n = r % NTOK;
    float res = 1.f;
    if (n > 0) {
        const float* p = mask + (size_t)(b * (NTOK - 1) + (n - 1)) * DIM;
        float s = 0.f;
        for (int i = lane; i < DIM; i += 64) s += p[i];
#pragma unroll
        for (int off = 32; off > 0; off >>= 1) s += __shfl_xor(s, off, 64);
        res = (s > 0.f) ? 1.f : 0.f;
    }
    if (lane == 0) upd[r] = res;
}

// ---------------------------------------------------------------------------
// K3: qe=bf16(q*qm*scale) [bh,1088,64], ke=bf16(k*km), vt=bf16 transposed
//     [bh,128,1088] with cols 0:64 = v*vm, 64:128 = vm (zeros for n>=NTOK)
// ---------------------------------------------------------------------------
__global__ __launch_bounds__(TPB)
void k_prep(const float* __restrict__ qkv, const float* __restrict__ qkvm,
            const float* __restrict__ cmax, unsigned short* __restrict__ qe,
            unsigned short* __restrict__ ke, unsigned short* __restrict__ vt)
{
    __shared__ unsigned short Vt_l[128 * 66];   // stride 66: 2-way-free write banks
    const int t = threadIdx.x;
    const int nt = blockIdx.x, h = blockIdx.y, b = blockIdx.z;
    const int bh = b * HEADS + h;
    const int nl = t >> 2, ds0 = (t & 3) * 16;
    const int n = nt * 64 + nl;
    const bool valid = n < NTOK;
    const int col0 = h * DH + ds0;

    unsigned short oq[16] __attribute__((aligned(16)));
    unsigned short ok[16] __attribute__((aligned(16)));

    const size_t row  = (size_t)(b * NTOK + n) * QK3 + col0;
    const size_t mrow = (size_t)(b * 1024 + (n - 1)) * QK3 + col0;
    const int cb = b * QK3 + col0;

#pragma unroll
    for (int i = 0; i < 4; ++i) {
        float qa[4] = {0, 0, 0, 0}, ka[4] = {0, 0, 0, 0}, va[4] = {0, 0, 0, 0};
        float qma[4] = {1, 1, 1, 1}, kma[4] = {1, 1, 1, 1}, vma[4] = {1, 1, 1, 1};
        if (valid) {
            *(float4*)qa = *(const float4*)(qkv + row + i * 4);
            *(float4*)ka = *(const float4*)(qkv + row + 768 + i * 4);
            *(float4*)va = *(const float4*)(qkv + row + 1536 + i * 4);
            if (n > 0) {
                *(float4*)qma = *(const float4*)(qkvm + mrow + i * 4);
                *(float4*)kma = *(const float4*)(qkvm + mrow + 768 + i * 4);
                *(float4*)vma = *(const float4*)(qkvm + mrow + 1536 + i * 4);
#pragma unroll
                for (int j = 0; j < 4; ++j) {
                    qma[j] /= (1e-6f + cmax[cb + i * 4 + j]);
                    kma[j] /= (1e-6f + cmax[cb + 768 + i * 4 + j]);
                    vma[j] /= (1e-6f + cmax[cb + 1536 + i * 4 + j]);
                }
            }
        }
#pragma unroll
        for (int j = 0; j < 4; ++j) {
            const int idx = i * 4 + j, d = ds0 + idx;
            oq[idx] = f2bf(qa[j] * qma[j] * 0.125f);
            ok[idx] = f2bf(ka[j] * kma[j]);
            const float vmv = valid ? vma[j] : 0.f;
            Vt_l[d * 66 + nl]        = f2bf(va[j] * vmv);
            Vt_l[(64 + d) * 66 + nl] = f2bf(vmv);
        }
    }
    if (valid) {
        unsigned short* qp = qe + ((size_t)bh * NPAD + n) * 64 + ds0;
        unsigned short* kp = ke + ((size_t)bh * NPAD + n) * 64 + ds0;
        *(short8*)qp       = *(short8*)oq;
        *(short8*)(qp + 8) = *(short8*)(oq + 8);
        *(short8*)kp       = *(short8*)ok;
        *(short8*)(kp + 8) = *(short8*)(ok + 8);
    }
    __syncthreads();
    const int c = t >> 1, nh = (t & 1) * 32;
    unsigned short ov[32] __attribute__((aligned(16)));
#pragma unroll
    for (int i = 0; i < 32; ++i) ov[i] = Vt_l[c * 66 + nh + i];
    unsigned short* vp = vt + ((size_t)bh * 128 + c) * NPAD + nt * 64 + nh;
#pragma unroll
    for (int i = 0; i < 4; ++i) *(short8*)(vp + i * 8) = *(short8*)(ov + i * 8);
}

// ---------------------------------------------------------------------------
// K4: MFMA flash attention. 4 waves x 16 q-rows = 64 q/block, kv tile 64.
// Fragment-order LDS: group g, slot = lane, 16 B each (conflict-free b128).
//   S = Q K^T via mfma(qf, kf);  C layout: row=quad*4+reg (q), col=lane&15 (kv)
//   P -> LDS (A-layout) -> PV via mfma(pf, vf) into 128-wide acc
// ---------------------------------------------------------------------------
__global__ __launch_bounds__(TPB)
void k_attn(const unsigned short* __restrict__ qe, const unsigned short* __restrict__ ke,
            const unsigned short* __restrict__ vt, float* __restrict__ o12)
{
    __shared__ short8 KsF[8 * 64];    // g = kk*4 + nc  (kk over d, nc over kv cols)
    __shared__ short8 VsF[16 * 64];   // g = kk*8 + nc8 (kk over kv,  nc8 over 128 out cols)
    __shared__ short8 PsF[8 * 64];    // per wave: 2 groups (kk over kv)

    const int t = threadIdx.x;
    const int w = t >> 6, lane = t & 63;
    const int l15 = lane & 15, quad = lane >> 4;
    const int bh = blockIdx.y;
    const int q0 = blockIdx.x * 64;

    // Q fragments (A-operand), registers for the whole block row
    short8 qf0, qf1;
    {
        const unsigned short* qp = qe + ((size_t)bh * NPAD + q0 + w * 16 + l15) * 64 + (quad << 3);
        qf0 = *(const short8*)qp;
        qf1 = *(const short8*)(qp + 32);
    }

    float m_i[4], l_i[4];
    f32x4 acc[8];
#pragma unroll
    for (int r = 0; r < 4; ++r) { m_i[r] = -INFINITY; l_i[r] = 0.f; }
#pragma unroll
    for (int g = 0; g < 8; ++g) acc[g] = (f32x4){0.f, 0.f, 0.f, 0.f};

    for (int kt = 0; kt < 17; ++kt) {
        const int kn0 = kt * 64;
        __syncthreads();
        // stage K tile: wave w writes groups 2w, 2w+1
#pragma unroll
        for (int gi = 0; gi < 2; ++gi) {
            const int g = 2 * w + gi, kk = g >> 2, nc = g & 3;
            const size_t krow = (size_t)bh * NPAD + kn0 + nc * 16 + l15;
            KsF[g * 64 + lane] = *(const short8*)(ke + krow * 64 + kk * 32 + (quad << 3));
        }
        // stage V tile: wave w writes groups 4w..4w+3
#pragma unroll
        for (int gi = 0; gi < 4; ++gi) {
            const int g = 4 * w + gi, kk = g >> 3, nc8 = g & 7;
            const size_t vrow = (size_t)bh * 128 + nc8 * 16 + l15;
            VsF[g * 64 + lane] = *(const short8*)(vt + vrow * NPAD + kn0 + kk * 32 + (quad << 3));
        }
        __syncthreads();

        // S = Q K^T
        f32x4 s[4];
#pragma unroll
        for (int nc = 0; nc < 4; ++nc) {
            f32x4 z = (f32x4){0.f, 0.f, 0.f, 0.f};
            z = __builtin_amdgcn_mfma_f32_16x16x32_bf16(qf0, KsF[nc * 64 + lane], z, 0, 0, 0);
            z = __builtin_amdgcn_mfma_f32_16x16x32_bf16(qf1, KsF[(4 + nc) * 64 + lane], z, 0, 0, 0);
            s[nc] = z;
        }
        // mask invalid kv cols
#pragma unroll
        for (int nc = 0; nc < 4; ++nc) {
            if (kn0 + nc * 16 + l15 >= NTOK) {
                s[nc][0] = -INFINITY; s[nc][1] = -INFINITY;
                s[nc][2] = -INFINITY; s[nc][3] = -INFINITY;
            }
        }
        // online softmax; lane owns rows quad*4 + r; kv reduction is quad-local
        float mx[4], sum[4], alpha[4];
#pragma unroll
        for (int r = 0; r < 4; ++r)
            mx[r] = fmaxf(fmaxf(s[0][r], s[1][r]), fmaxf(s[2][r], s[3][r]));
#pragma unroll
        for (int r = 0; r < 4; ++r) {
            mx[r] = fmaxf(mx[r], __shfl_xor(mx[r], 1, 64));
            mx[r] = fmaxf(mx[r], __shfl_xor(mx[r], 2, 64));
            mx[r] = fmaxf(mx[r], __shfl_xor(mx[r], 4, 64));
            mx[r] = fmaxf(mx[r], __shfl_xor(mx[r], 8, 64));
        }
#pragma unroll
        for (int r = 0; r < 4; ++r) {
            const float mnew = fmaxf(m_i[r], mx[r]);
            alpha[r] = __expf(m_i[r] - mnew);
            m_i[r] = mnew;
            sum[r] = 0.f;
        }
#pragma unroll
        for (int nc = 0; nc < 4; ++nc)
#pragma unroll
            for (int r = 0; r < 4; ++r) {
                const float p = __expf(s[nc][r] - m_i[r]);
                s[nc][r] = p;
                sum[r] += p;
            }
#pragma unroll
        for (int r = 0; r < 4; ++r) {
            sum[r] += __shfl_xor(sum[r], 1, 64);
            sum[r] += __shfl_xor(sum[r], 2, 64);
            sum[r] += __shfl_xor(sum[r], 4, 64);
            sum[r] += __shfl_xor(sum[r], 8, 64);
            l_i[r] = l_i[r] * alpha[r] + sum[r];
        }
#pragma unroll
        for (int g = 0; g < 8; ++g) {
            acc[g][0] *= alpha[0]; acc[g][1] *= alpha[1];
            acc[g][2] *= alpha[2]; acc[g][3] *= alpha[3];
        }
        // P: C-layout regs -> A-layout LDS (wave-private, no barrier needed)
        unsigned short* Pw = (unsigned short*)&PsF[w * 2 * 64];
#pragma unroll
        for (int nc = 0; nc < 4; ++nc) {
            const int k = nc * 16 + l15;
            const int kk = nc >> 1;
            const int slotbase = ((k >> 3) & 3) << 4;
            const int j = k & 7;
#pragma unroll
            for (int r = 0; r < 4; ++r)
                Pw[kk * 512 + (quad * 4 + r + slotbase) * 8 + j] = f2bf(s[nc][r]);
        }
        const short8 pf0 = PsF[(w * 2 + 0) * 64 + lane];
        const short8 pf1 = PsF[(w * 2 + 1) * 64 + lane];
        // O += P V  (128-wide)
#pragma unroll
        for (int nc8 = 0; nc8 < 8; ++nc8) {
            acc[nc8] = __builtin_amdgcn_mfma_f32_16x16x32_bf16(pf0, VsF[nc8 * 64 + lane], acc[nc8], 0, 0, 0);
            acc[nc8] = __builtin_amdgcn_mfma_f32_16x16x32_bf16(pf1, VsF[(8 + nc8) * 64 + lane], acc[nc8], 0, 0, 0);
        }
    }

#pragma unroll
    for (int r = 0; r < 4; ++r) {
        const int row = q0 + w * 16 + quad * 4 + r;
        if (row < NTOK) {
            const float inv = 1.f / l_i[r];
            float* op = o12 + ((size_t)bh * NTOK + row) * 128 + l15;
#pragma unroll
            for (int nc8 = 0; nc8 < 8; ++nc8) op[nc8 * 16] = acc[nc8][r] * inv;
        }
    }
}

// ---------------------------------------------------------------------------
// K5: final GEMMs (unchanged fp32)
// ---------------------------------------------------------------------------
__global__ __launch_bounds__(TPB)
void k_gemm_out(const float* __restrict__ o12, const float* __restrict__ upd,
                const float* __restrict__ wout, const float* __restrict__ bout,
                float* __restrict__ dout)
{
    const int z = blockIdx.z;
    __shared__ float As[8][128];
    __shared__ float Bs[8][128];

    const int t = threadIdx.x;
    const int tx = t & 15, ty = t >> 4;
    const int rowT = blockIdx.y * 128, colT = blockIdx.x * 128;
    const int lr = t >> 1, lk = (t & 1) * 4;
    const int arow = rowT + lr;
    const bool aval = arow < ROWS;
    const int ab = aval ? (arow / NTOK) : 0;
    const int an = aval ? (arow % NTOK) : 0;
    const float u = aval ? upd[arow] : 0.f;
    const int brow = colT + lr;
    const float* Bp = wout + (size_t)brow * DIM + lk;
    const size_t abase = ((size_t)ab * HEADS * NTOK + an) * 128 + (z ? 64 : 0);

    float acc[8][8];
#pragma unroll
    for (int i = 0; i < 8; ++i)
#pragma unroll
        for (int j = 0; j < 8; ++j) acc[i][j] = 0.f;

    for (int k0 = 0; k0 < DIM; k0 += 8) {
        const int c = k0 + lk;
        const int h = c >> 6, d = c & 63;
        float4 av = make_float4(0.f, 0.f, 0.f, 0.f);
        if (aval) {
            av = *(const float4*)(o12 + abase + (size_t)h * NTOK * 128 + d);
            av.x *= u; av.y *= u; av.z *= u; av.w *= u;
        }
        float4 bv = *(const float4*)(Bp + k0);
        if (z) { bv.x = fabsf(bv.x); bv.y = fabsf(bv.y); bv.z = fabsf(bv.z); bv.w = fabsf(bv.w); }
        __syncthreads();
        As[lk + 0][lr] = av.x; As[lk + 1][lr] = av.y; As[lk + 2][lr] = av.z; As[lk + 3][lr] = av.w;
        Bs[lk + 0][lr] = bv.x; Bs[lk + 1][lr] = bv.y; Bs[lk + 2][lr] = bv.z; Bs[lk + 3][lr] = bv.w;
        __syncthreads();
#pragma unroll
        for (int k = 0; k < 8; ++k) {
            float ar[8], br[8];
            *(float4*)&ar[0] = *(const float4*)&As[k][ty * 4];
            *(float4*)&ar[4] = *(const float4*)&As[k][64 + ty * 4];
            *(float4*)&br[0] = *(const float4*)&Bs[k][tx * 4];
            *(float4*)&br[4] = *(const float4*)&Bs[k][64 + tx * 4];
#pragma unroll
            for (int i = 0; i < 8; ++i)
#pragma unroll
                for (int j = 0; j < 8; ++j)
                    acc[i][j] = fmaf(ar[i], br[j], acc[i][j]);
        }
    }
#pragma unroll
    for (int i = 0; i < 8; ++i) {
        const int r = rowT + ((i < 4) ? (ty * 4 + i) : (64 + ty * 4 + i - 4));
        if (r >= ROWS) continue;
        const int b = r / NTOK, n = r % NTOK;
#pragma unroll
        for (int g = 0; g < 2; ++g) {
            const int col = colT + g * 64 + tx * 4;
            float4 v = make_float4(acc[i][g * 4 + 0], acc[i][g * 4 + 1],
                                   acc[i][g * 4 + 2], acc[i][g * 4 + 3]);
            if (z == 0) {
                const float4 bb = *(const float4*)(bout + col);
                v.x += bb.x; v.y += bb.y; v.z += bb.z; v.w += bb.w;
                *(float4*)(dout + (size_t)r * DIM + col) = v;
            } else if (n >= 1) {
                *(float4*)(dout + OUT0 + ((size_t)(b * (NTOK - 1) + (n - 1))) * DIM + col) = v;
            }
        }
    }
}

extern "C" void kernel_launch(void* const* d_in, const int* in_sizes, int n_in,
                              void* d_out, int out_size, void* d_ws, size_t ws_size,
                              hipStream_t stream)
{
    const float* x    = (const float*)d_in[0];
    const float* mask = (const float*)d_in[1];
    const float* wqkv = (const float*)d_in[2];
    const float* wout = (const float*)d_in[3];
    const float* bout = (const float*)d_in[4];
    float* ws   = (float*)d_ws;
    float* qkv  = ws + OFF_QKV;
    float* qkvm = ws + OFF_QKVM;
    unsigned short* qe = (unsigned short*)(ws + OFF_QE);
    unsigned short* ke = (unsigned short*)(ws + OFF_KE);
    unsigned short* vt = (unsigned short*)(ws + OFF_VT);
    float* cmax = ws + OFF_CMAX;
    float* upd  = ws + OFF_UPD;
    float* o12  = ws + OFF_O12;   // aliases qkv (dead after k_prep)
    float* out  = (float*)d_out;

    hipLaunchKernelGGL(k_gemm_qkv, dim3(18, 33, 2), dim3(TPB), 0, stream, x, mask, wqkv, qkv, qkvm);
    hipLaunchKernelGGL(k_colmax,   dim3(36, 4),     dim3(TPB), 0, stream, qkvm, cmax);
    hipLaunchKernelGGL(k_upd,      dim3(1025),      dim3(TPB), 0, stream, mask, upd);
    hipLaunchKernelGGL(k_prep,     dim3(17, 12, 4), dim3(TPB), 0, stream, qkv, qkvm, cmax, qe, ke, vt);
    hipLaunchKernelGGL(k_attn,     dim3(17, 48),    dim3(TPB), 0, stream, qe, ke, vt, o12);
    hipLaunchKernelGGL(k_gemm_out, dim3(6, 33, 2),  dim3(TPB), 0, stream, o12, upd, wout, bout, out);
}

// Round 3
// 379.894 us; speedup vs baseline: 3.6264x; 2.1404x over previous
//
#include <hip/hip_runtime.h>
#include <cmath>

#define TPB 256

static const int NTOK  = 1025;
static const int DIM   = 768;
static const int HEADS = 12;
static const int DH    = 64;
static const int QK3   = 2304;
static const int ROWS  = 4 * NTOK;        // 4100
static const int MROWS = 4 * (NTOK - 1);  // 4096
static const int MPAD  = 4224;            // 33*128 padded A rows
static const int NPAD  = 1088;            // 17*64
static const size_t OUT0 = (size_t)ROWS * DIM;
static const size_t APLANE = (size_t)MPAD * DIM;   // 3,244,032 bf16 per plane

// workspace offsets in floats
static const size_t OFF_QKV  = 0;          // 9,446,400 f
static const size_t OFF_QKVM = 9446400;    // 9,437,184 f
static const size_t OFF_QE   = 18883584;   // 1,671,168 f (bf16)
static const size_t OFF_KE   = 20554752;   // 1,671,168 f
static const size_t OFF_VT   = 22225920;   // 3,342,336 f
static const size_t OFF_ABF  = 25568256;   // bf16 [2][4224][768] = 3,244,032 f  (x/mask, later attn out)
static const size_t OFF_WQ   = 28812288;   // bf16 [2][2304][768] = 1,769,472 f
static const size_t OFF_WO   = 30581760;   // bf16 [2][768][768]  =   589,824 f
static const size_t OFF_CMAX = 31171584;   // 9,216 f
static const size_t OFF_UPD  = 31180800;   // 4,100 f

typedef __attribute__((ext_vector_type(8))) short short8;
typedef __attribute__((ext_vector_type(4))) float f32x4;

__device__ __forceinline__ unsigned short f2bf(float f) {
    union { float f; unsigned int u; } c; c.f = f;
    unsigned int u = c.u + 0x7fffu + ((c.u >> 16) & 1u);  // RNE
    return (unsigned short)(u >> 16);
}

__device__ __forceinline__ void gl_lds16(const unsigned short* g, unsigned short* l) {
    __builtin_amdgcn_global_load_lds(
        (const __attribute__((address_space(1))) unsigned int*)g,
        (__attribute__((address_space(3))) unsigned int*)l, 16, 0, 0);
}

// ---------------------------------------------------------------------------
// K0: fp32 -> bf16 conversions.
// z=0: x    -> Abf plane0 (rows<4100, zero pad)
// z=1: mask -> Abf plane1 (rows<4096, zero pad)
// z=2: wqkv -> Wq plane0 (w), plane1 (|w|)
// z=3: wout -> Wo plane0 (w), plane1 (|w|)
// ---------------------------------------------------------------------------
__global__ __launch_bounds__(TPB)
void k_cvt(const float* __restrict__ x, const float* __restrict__ mask,
           const float* __restrict__ wqkv, const float* __restrict__ wout,
           unsigned short* __restrict__ Abf, unsigned short* __restrict__ Wq,
           unsigned short* __restrict__ Wo)
{
    const int z = blockIdx.z;
    const size_t idx = ((size_t)blockIdx.x * TPB + threadIdx.x) * 8;
    unsigned short o[8] __attribute__((aligned(16)));
    if (z <= 1) {
        if (idx >= APLANE) return;
        const int row = (int)(idx / DIM);
        const int M = z ? MROWS : ROWS;
        const float* src = z ? mask : x;
        if (row < M) {
            float a[8];
            *(float4*)&a[0] = *(const float4*)(src + idx);
            *(float4*)&a[4] = *(const float4*)(src + idx + 4);
#pragma unroll
            for (int i = 0; i < 8; ++i) o[i] = f2bf(a[i]);
        } else {
#pragma unroll
            for (int i = 0; i < 8; ++i) o[i] = 0;
        }
        *(short8*)(Abf + (size_t)z * APLANE + idx) = *(short8*)o;
    } else {
        const size_t tot = (z == 2) ? (size_t)QK3 * DIM : (size_t)DIM * DIM;
        if (idx >= tot) return;
        const float* src = (z == 2) ? wqkv : wout;
        unsigned short* dst = (z == 2) ? Wq : Wo;
        float a[8];
        *(float4*)&a[0] = *(const float4*)(src + idx);
        *(float4*)&a[4] = *(const float4*)(src + idx + 4);
        unsigned short oa[8] __attribute__((aligned(16)));
#pragma unroll
        for (int i = 0; i < 8; ++i) { o[i] = f2bf(a[i]); oa[i] = f2bf(fabsf(a[i])); }
        *(short8*)(dst + idx) = *(short8*)o;
        *(short8*)(dst + tot + idx) = *(short8*)oa;
    }
}

// ---------------------------------------------------------------------------
// K1: bf16 MFMA GEMM (m97 recipe): C[m,n] = sum_k A[m,k]*B[n,k], fp32 out.
// z=0: qkv = x @ w^T ; z=1: qkv_m = mask @ |w|^T
// ---------------------------------------------------------------------------
__global__ __launch_bounds__(TPB)
void k_gemm_qkv_mfma(const unsigned short* __restrict__ Abf,
                     const unsigned short* __restrict__ Wq,
                     float* __restrict__ qkv, float* __restrict__ qkvm)
{
    const int z = blockIdx.z;
    const unsigned short* A = Abf + (size_t)z * APLANE;
    const unsigned short* B = Wq + (size_t)z * QK3 * DIM;
    float* C = z ? qkvm : qkv;
    const int M = z ? MROWS : ROWS;

    __shared__ unsigned short As[128 * 32];
    __shared__ unsigned short Bs[128 * 32];

    const int t = threadIdx.x;
    const int w = t >> 6, lane = t & 63, l15 = lane & 15, quad = lane >> 4;
    const int rowT = blockIdx.y * 128, colT = blockIdx.x * 128;
    const int wm = (w & 1) * 64, wn = (w >> 1) * 64;

    const int r0 = t >> 2, kc = (t & 3) * 8;
    const unsigned short* Ap = A + (size_t)(rowT + r0) * DIM + kc;
    const unsigned short* Bp = B + (size_t)(colT + r0) * DIM + kc;

    f32x4 acc[4][4];
#pragma unroll
    for (int i = 0; i < 4; ++i)
#pragma unroll
        for (int j = 0; j < 4; ++j) acc[i][j] = (f32x4){0.f, 0.f, 0.f, 0.f};

    for (int k0 = 0; k0 < DIM; k0 += 32) {
        __syncthreads();
        gl_lds16(Ap + k0,            As + t * 8);
        gl_lds16(Ap + 64 * DIM + k0, As + (t + 256) * 8);
        gl_lds16(Bp + k0,            Bs + t * 8);
        gl_lds16(Bp + 64 * DIM + k0, Bs + (t + 256) * 8);
        __syncthreads();
        short8 fa[4], fb[4];
#pragma unroll
        for (int mi = 0; mi < 4; ++mi)
            fa[mi] = *(const short8*)(As + (wm + mi * 16 + l15) * 32 + quad * 8);
#pragma unroll
        for (int ni = 0; ni < 4; ++ni)
            fb[ni] = *(const short8*)(Bs + (wn + ni * 16 + l15) * 32 + quad * 8);
#pragma unroll
        for (int mi = 0; mi < 4; ++mi)
#pragma unroll
            for (int ni = 0; ni < 4; ++ni)
                acc[mi][ni] = __builtin_amdgcn_mfma_f32_16x16x32_bf16(fa[mi], fb[ni], acc[mi][ni], 0, 0, 0);
    }
#pragma unroll
    for (int mi = 0; mi < 4; ++mi)
#pragma unroll
        for (int ni = 0; ni < 4; ++ni) {
            const int col = colT + wn + ni * 16 + l15;
#pragma unroll
            for (int r = 0; r < 4; ++r) {
                const int row = rowT + wm + mi * 16 + quad * 4 + r;
                if (row < M) C[(size_t)row * QK3 + col] = acc[mi][ni][r];
            }
        }
}

// ---------------------------------------------------------------------------
// K2a: column max of qkv_m over the 1024 tokens, per (b, col)
// ---------------------------------------------------------------------------
__global__ __launch_bounds__(TPB)
void k_colmax(const float* __restrict__ qkvm, float* __restrict__ cmax)
{
    __shared__ float red[4][64];
    const int t = threadIdx.x;
    const int cl = t & 63, rg = t >> 6;
    const int col = blockIdx.x * 64 + cl;
    const int b = blockIdx.y;
    const float* p = qkvm + (size_t)b * 1024 * QK3 + col;
    float mx = 0.f;
    const int n0 = rg * 256;
    for (int n = 0; n < 256; ++n) mx = fmaxf(mx, p[(size_t)(n0 + n) * QK3]);
    red[rg][cl] = mx;
    __syncthreads();
    if (rg == 0) {
        mx = fmaxf(fmaxf(red[0][cl], red[1][cl]), fmaxf(red[2][cl], red[3][cl]));
        cmax[b * QK3 + col] = mx;
    }
}

// ---------------------------------------------------------------------------
// K2b: updated[b,n]
// ---------------------------------------------------------------------------
__global__ __launch_bounds__(TPB)
void k_upd(const float* __restrict__ mask, float* __restrict__ upd)
{
    const int w = threadIdx.x >> 6, lane = threadIdx.x & 63;
    const int r = blockIdx.x * 4 + w;
    if (r >= ROWS) return;
    const int b = r / NTOK, n = r % NTOK;
    float res = 1.f;
    if (n > 0) {
        const float* p = mask + (size_t)(b * (NTOK - 1) + (n - 1)) * DIM;
        float s = 0.f;
        for (int i = lane; i < DIM; i += 64) s += p[i];
#pragma unroll
        for (int off = 32; off > 0; off >>= 1) s += __shfl_xor(s, off, 64);
        res = (s > 0.f) ? 1.f : 0.f;
    }
    if (lane == 0) upd[r] = res;
}

// ---------------------------------------------------------------------------
// K3: qe/ke bf16 [bh,1088,64], vt bf16 transposed [bh,128,1088]
// ---------------------------------------------------------------------------
__global__ __launch_bounds__(TPB)
void k_prep(const float* __restrict__ qkv, const float* __restrict__ qkvm,
            const float* __restrict__ cmax, unsigned short* __restrict__ qe,
            unsigned short* __restrict__ ke, unsigned short* __restrict__ vt)
{
    __shared__ unsigned short Vt_l[128 * 66];
    const int t = threadIdx.x;
    const int nt = blockIdx.x, h = blockIdx.y, b = blockIdx.z;
    const int bh = b * HEADS + h;
    const int nl = t >> 2, ds0 = (t & 3) * 16;
    const int n = nt * 64 + nl;
    const bool valid = n < NTOK;
    const int col0 = h * DH + ds0;

    unsigned short oq[16] __attribute__((aligned(16)));
    unsigned short ok[16] __attribute__((aligned(16)));

    const size_t row  = (size_t)(b * NTOK + n) * QK3 + col0;
    const size_t mrow = (size_t)(b * 1024 + (n - 1)) * QK3 + col0;
    const int cb = b * QK3 + col0;

#pragma unroll
    for (int i = 0; i < 4; ++i) {
        float qa[4] = {0, 0, 0, 0}, ka[4] = {0, 0, 0, 0}, va[4] = {0, 0, 0, 0};
        float qma[4] = {1, 1, 1, 1}, kma[4] = {1, 1, 1, 1}, vma[4] = {1, 1, 1, 1};
        if (valid) {
            *(float4*)qa = *(const float4*)(qkv + row + i * 4);
            *(float4*)ka = *(const float4*)(qkv + row + 768 + i * 4);
            *(float4*)va = *(const float4*)(qkv + row + 1536 + i * 4);
            if (n > 0) {
                *(float4*)qma = *(const float4*)(qkvm + mrow + i * 4);
                *(float4*)kma = *(const float4*)(qkvm + mrow + 768 + i * 4);
                *(float4*)vma = *(const float4*)(qkvm + mrow + 1536 + i * 4);
#pragma unroll
                for (int j = 0; j < 4; ++j) {
                    qma[j] /= (1e-6f + cmax[cb + i * 4 + j]);
                    kma[j] /= (1e-6f + cmax[cb + 768 + i * 4 + j]);
                    vma[j] /= (1e-6f + cmax[cb + 1536 + i * 4 + j]);
                }
            }
        }
#pragma unroll
        for (int j = 0; j < 4; ++j) {
            const int idx = i * 4 + j, d = ds0 + idx;
            oq[idx] = f2bf(qa[j] * qma[j] * 0.125f);
            ok[idx] = f2bf(ka[j] * kma[j]);
            const float vmv = valid ? vma[j] : 0.f;
            Vt_l[d * 66 + nl]        = f2bf(va[j] * vmv);
            Vt_l[(64 + d) * 66 + nl] = f2bf(vmv);
        }
    }
    if (valid) {
        unsigned short* qp = qe + ((size_t)bh * NPAD + n) * 64 + ds0;
        unsigned short* kp = ke + ((size_t)bh * NPAD + n) * 64 + ds0;
        *(short8*)qp       = *(short8*)oq;
        *(short8*)(qp + 8) = *(short8*)(oq + 8);
        *(short8*)kp       = *(short8*)ok;
        *(short8*)(kp + 8) = *(short8*)(ok + 8);
    }
    __syncthreads();
    const int c = t >> 1, nh = (t & 1) * 32;
    unsigned short ov[32] __attribute__((aligned(16)));
#pragma unroll
    for (int i = 0; i < 32; ++i) ov[i] = Vt_l[c * 66 + nh + i];
    unsigned short* vp = vt + ((size_t)bh * 128 + c) * NPAD + nt * 64 + nh;
#pragma unroll
    for (int i = 0; i < 4; ++i) *(short8*)(vp + i * 8) = *(short8*)(ov + i * 8);
}

// ---------------------------------------------------------------------------
// K4: MFMA flash attention. Epilogue writes bf16 into packed A2 layout
// [plane][b*1025+n][h*64+d] with `updated` applied (A for the out-GEMMs).
// ---------------------------------------------------------------------------
__global__ __launch_bounds__(TPB)
void k_attn(const unsigned short* __restrict__ qe, const unsigned short* __restrict__ ke,
            const unsigned short* __restrict__ vt, const float* __restrict__ upd,
            unsigned short* __restrict__ ab2)
{
    __shared__ short8 KsF[8 * 64];
    __shared__ short8 VsF[16 * 64];
    __shared__ short8 PsF[8 * 64];

    const int t = threadIdx.x;
    const int w = t >> 6, lane = t & 63;
    const int l15 = lane & 15, quad = lane >> 4;
    const int bh = blockIdx.y;
    const int b = bh / HEADS, h = bh % HEADS;
    const int q0 = blockIdx.x * 64;

    short8 qf0, qf1;
    {
        const unsigned short* qp = qe + ((size_t)bh * NPAD + q0 + w * 16 + l15) * 64 + (quad << 3);
        qf0 = *(const short8*)qp;
        qf1 = *(const short8*)(qp + 32);
    }

    float m_i[4], l_i[4];
    f32x4 acc[8];
#pragma unroll
    for (int r = 0; r < 4; ++r) { m_i[r] = -INFINITY; l_i[r] = 0.f; }
#pragma unroll
    for (int g = 0; g < 8; ++g) acc[g] = (f32x4){0.f, 0.f, 0.f, 0.f};

    for (int kt = 0; kt < 17; ++kt) {
        const int kn0 = kt * 64;
        __syncthreads();
#pragma unroll
        for (int gi = 0; gi < 2; ++gi) {
            const int g = 2 * w + gi, kk = g >> 2, nc = g & 3;
            const size_t krow = (size_t)bh * NPAD + kn0 + nc * 16 + l15;
            KsF[g * 64 + lane] = *(const short8*)(ke + krow * 64 + kk * 32 + (quad << 3));
        }
#pragma unroll
        for (int gi = 0; gi < 4; ++gi) {
            const int g = 4 * w + gi, kk = g >> 3, nc8 = g & 7;
            const size_t vrow = (size_t)bh * 128 + nc8 * 16 + l15;
            VsF[g * 64 + lane] = *(const short8*)(vt + vrow * NPAD + kn0 + kk * 32 + (quad << 3));
        }
        __syncthreads();

        f32x4 s[4];
#pragma unroll
        for (int nc = 0; nc < 4; ++nc) {
            f32x4 z = (f32x4){0.f, 0.f, 0.f, 0.f};
            z = __builtin_amdgcn_mfma_f32_16x16x32_bf16(qf0, KsF[nc * 64 + lane], z, 0, 0, 0);
            z = __builtin_amdgcn_mfma_f32_16x16x32_bf16(qf1, KsF[(4 + nc) * 64 + lane], z, 0, 0, 0);
            s[nc] = z;
        }
#pragma unroll
        for (int nc = 0; nc < 4; ++nc) {
            if (kn0 + nc * 16 + l15 >= NTOK) {
                s[nc][0] = -INFINITY; s[nc][1] = -INFINITY;
                s[nc][2] = -INFINITY; s[nc][3] = -INFINITY;
            }
        }
        float mx[4], sum[4], alpha[4];
#pragma unroll
        for (int r = 0; r < 4; ++r)
            mx[r] = fmaxf(fmaxf(s[0][r], s[1][r]), fmaxf(s[2][r], s[3][r]));
#pragma unroll
        for (int r = 0; r < 4; ++r) {
            mx[r] = fmaxf(mx[r], __shfl_xor(mx[r], 1, 64));
            mx[r] = fmaxf(mx[r], __shfl_xor(mx[r], 2, 64));
            mx[r] = fmaxf(mx[r], __shfl_xor(mx[r], 4, 64));
            mx[r] = fmaxf(mx[r], __shfl_xor(mx[r], 8, 64));
        }
#pragma unroll
        for (int r = 0; r < 4; ++r) {
            const float mnew = fmaxf(m_i[r], mx[r]);
            alpha[r] = __expf(m_i[r] - mnew);
            m_i[r] = mnew;
            sum[r] = 0.f;
        }
#pragma unroll
        for (int nc = 0; nc < 4; ++nc)
#pragma unroll
            for (int r = 0; r < 4; ++r) {
                const float p = __expf(s[nc][r] - m_i[r]);
                s[nc][r] = p;
                sum[r] += p;
            }
#pragma unroll
        for (int r = 0; r < 4; ++r) {
            sum[r] += __shfl_xor(sum[r], 1, 64);
            sum[r] += __shfl_xor(sum[r], 2, 64);
            sum[r] += __shfl_xor(sum[r], 4, 64);
            sum[r] += __shfl_xor(sum[r], 8, 64);
            l_i[r] = l_i[r] * alpha[r] + sum[r];
        }
#pragma unroll
        for (int g = 0; g < 8; ++g) {
            acc[g][0] *= alpha[0]; acc[g][1] *= alpha[1];
            acc[g][2] *= alpha[2]; acc[g][3] *= alpha[3];
        }
        unsigned short* Pw = (unsigned short*)&PsF[w * 2 * 64];
#pragma unroll
        for (int nc = 0; nc < 4; ++nc) {
            const int k = nc * 16 + l15;
            const int kk = nc >> 1;
            const int slotbase = ((k >> 3) & 3) << 4;
            const int j = k & 7;
#pragma unroll
            for (int r = 0; r < 4; ++r)
                Pw[kk * 512 + (quad * 4 + r + slotbase) * 8 + j] = f2bf(s[nc][r]);
        }
        const short8 pf0 = PsF[(w * 2 + 0) * 64 + lane];
        const short8 pf1 = PsF[(w * 2 + 1) * 64 + lane];
#pragma unroll
        for (int nc8 = 0; nc8 < 8; ++nc8) {
            acc[nc8] = __builtin_amdgcn_mfma_f32_16x16x32_bf16(pf0, VsF[nc8 * 64 + lane], acc[nc8], 0, 0, 0);
            acc[nc8] = __builtin_amdgcn_mfma_f32_16x16x32_bf16(pf1, VsF[(8 + nc8) * 64 + lane], acc[nc8], 0, 0, 0);
        }
    }

#pragma unroll
    for (int r = 0; r < 4; ++r) {
        const int row = q0 + w * 16 + quad * 4 + r;
        if (row < NTOK) {
            const size_t rg = (size_t)b * NTOK + row;
            const float inv = upd[rg] / l_i[r];
#pragma unroll
            for (int nc8 = 0; nc8 < 8; ++nc8) {
                const int c = nc8 * 16 + l15;
                const size_t addr = (size_t)(c >> 6) * APLANE + rg * DIM + h * 64 + (c & 63);
                ab2[addr] = f2bf(acc[nc8][r] * inv);
            }
        }
    }
}

// ---------------------------------------------------------------------------
// K5: bf16 MFMA out-GEMMs.
// z=0: out = A2p0 @ w_out^T + b_out -> dout[0:4100*768]
// z=1: m   = A2p1 @ |w_out|^T, rows n>=1 -> dout[OUT0:]
// ---------------------------------------------------------------------------
__global__ __launch_bounds__(TPB)
void k_gemm_out_mfma(const unsigned short* __restrict__ ab2,
                     const unsigned short* __restrict__ Wo,
                     const float* __restrict__ bout, float* __restrict__ dout)
{
    const int z = blockIdx.z;
    const unsigned short* A = ab2 + (size_t)z * APLANE;
    const unsigned short* B = Wo + (size_t)z * DIM * DIM;

    __shared__ unsigned short As[128 * 32];
    __shared__ unsigned short Bs[128 * 32];

    const int t = threadIdx.x;
    const int w = t >> 6, lane = t & 63, l15 = lane & 15, quad = lane >> 4;
    const int rowT = blockIdx.y * 128, colT = blockIdx.x * 128;
    const int wm = (w & 1) * 64, wn = (w >> 1) * 64;

    const int r0 = t >> 2, kc = (t & 3) * 8;
    const unsigned short* Ap = A + (size_t)(rowT + r0) * DIM + kc;
    const unsigned short* Bp = B + (size_t)(colT + r0) * DIM + kc;

    f32x4 acc[4][4];
#pragma unroll
    for (int i = 0; i < 4; ++i)
#pragma unroll
        for (int j = 0; j < 4; ++j) acc[i][j] = (f32x4){0.f, 0.f, 0.f, 0.f};

    for (int k0 = 0; k0 < DIM; k0 += 32) {
        __syncthreads();
        gl_lds16(Ap + k0,            As + t * 8);
        gl_lds16(Ap + 64 * DIM + k0, As + (t + 256) * 8);
        gl_lds16(Bp + k0,            Bs + t * 8);
        gl_lds16(Bp + 64 * DIM + k0, Bs + (t + 256) * 8);
        __syncthreads();
        short8 fa[4], fb[4];
#pragma unroll
        for (int mi = 0; mi < 4; ++mi)
            fa[mi] = *(const short8*)(As + (wm + mi * 16 + l15) * 32 + quad * 8);
#pragma unroll
        for (int ni = 0; ni < 4; ++ni)
            fb[ni] = *(const short8*)(Bs + (wn + ni * 16 + l15) * 32 + quad * 8);
#pragma unroll
        for (int mi = 0; mi < 4; ++mi)
#pragma unroll
            for (int ni = 0; ni < 4; ++ni)
                acc[mi][ni] = __builtin_amdgcn_mfma_f32_16x16x32_bf16(fa[mi], fb[ni], acc[mi][ni], 0, 0, 0);
    }
#pragma unroll
    for (int mi = 0; mi < 4; ++mi)
#pragma unroll
        for (int ni = 0; ni < 4; ++ni) {
            const int col = colT + wn + ni * 16 + l15;
            const float bb = (z == 0) ? bout[col] : 0.f;
#pragma unroll
            for (int r = 0; r < 4; ++r) {
                const int row = rowT + wm + mi * 16 + quad * 4 + r;
                if (row >= ROWS) continue;
                const int b = row / NTOK, n = row % NTOK;
                if (z == 0) {
                    dout[(size_t)row * DIM + col] = acc[mi][ni][r] + bb;
                } else if (n >= 1) {
                    dout[OUT0 + ((size_t)(b * (NTOK - 1) + (n - 1))) * DIM + col] = acc[mi][ni][r];
                }
            }
        }
}

extern "C" void kernel_launch(void* const* d_in, const int* in_sizes, int n_in,
                              void* d_out, int out_size, void* d_ws, size_t ws_size,
                              hipStream_t stream)
{
    const float* x    = (const float*)d_in[0];
    const float* mask = (const float*)d_in[1];
    const float* wqkv = (const float*)d_in[2];
    const float* wout = (const float*)d_in[3];
    const float* bout = (const float*)d_in[4];
    float* ws   = (float*)d_ws;
    float* qkv  = ws + OFF_QKV;
    float* qkvm = ws + OFF_QKVM;
    unsigned short* qe  = (unsigned short*)(ws + OFF_QE);
    unsigned short* ke  = (unsigned short*)(ws + OFF_KE);
    unsigned short* vt  = (unsigned short*)(ws + OFF_VT);
    unsigned short* abf = (unsigned short*)(ws + OFF_ABF);  // x/mask planes, then attn-out planes
    unsigned short* wq  = (unsigned short*)(ws + OFF_WQ);
    unsigned short* wo  = (unsigned short*)(ws + OFF_WO);
    float* cmax = ws + OFF_CMAX;
    float* upd  = ws + OFF_UPD;
    float* out  = (float*)d_out;

    hipLaunchKernelGGL(k_cvt,           dim3(1584, 1, 4), dim3(TPB), 0, stream, x, mask, wqkv, wout, abf, wq, wo);
    hipLaunchKernelGGL(k_gemm_qkv_mfma, dim3(18, 33, 2),  dim3(TPB), 0, stream, abf, wq, qkv, qkvm);
    hipLaunchKernelGGL(k_colmax,        dim3(36, 4),      dim3(TPB), 0, stream, qkvm, cmax);
    hipLaunchKernelGGL(k_upd,           dim3(1025),       dim3(TPB), 0, stream, mask, upd);
    hipLaunchKernelGGL(k_prep,          dim3(17, 12, 4),  dim3(TPB), 0, stream, qkv, qkvm, cmax, qe, ke, vt);
    hipLaunchKernelGGL(k_attn,          dim3(17, 48),     dim3(TPB), 0, stream, qe, ke, vt, upd, abf);
    hipLaunchKernelGGL(k_gemm_out_mfma, dim3(6, 33, 2),   dim3(TPB), 0, stream, abf, wo, bout, out);
}